// Round 1
// baseline (646.546 us; speedup 1.0000x reference)
//
#include <hip/hip_runtime.h>

// AdapLoss — (8,1,160,160,160) fp32. Memory-bound reduction, 262 MB read.
// R5 = R4 with (a) stage2 fused into stage1 via last-block-done reduction
// (4B memset + device-scope atomic counter; arithmetic order identical to
// the two-kernel version -> bitwise-deterministic), and (b) nontemporal
// loads replaced by plain loads (262 MB working set ~ L3 size; nt forfeits
// any L3 hits and its read-path peak is unverified).

#define TPB 256
#define BPS 500                            // blocks per sample
constexpr int    F4_PER_SAMPLE = 1024000;  // 160^3 / 4
constexpr int    F4_PER_BLOCK  = 2048;     // 8 float4/thread * 256 threads
constexpr int    NBLOCKS       = 8 * BPS;  // 4000
constexpr double PER_SAMPLE_D  = 4096000.0;
constexpr float  DELTA = 5.0f;

typedef float vf4 __attribute__((ext_vector_type(4)));

__global__ __launch_bounds__(TPB, 4) void adap_fused(
    const vf4* __restrict__ pred,
    const vf4* __restrict__ truth,
    float* __restrict__ part,           // [8][BPS][3] in workspace
    unsigned int* __restrict__ counter, // 1 uint in workspace, memset to 0
    float* __restrict__ out)
{
    const int s   = blockIdx.y;
    const int b   = blockIdx.x;
    const int tid = threadIdx.x;
    const int base = s * F4_PER_SAMPLE + b * F4_PER_BLOCK + tid;

    // Issue all 16 loads back-to-back, interleaved (p0,t0,p1,t1,...) so the
    // j-th consume only needs vmcnt(14-2j) — queue stays deep while consuming.
    vf4 p[8], t[8];
    #pragma unroll
    for (int j = 0; j < 8; ++j) {
        p[j] = pred [base + j * TPB];
        t[j] = truth[base + j * TPB];
    }

    float sum2 = 0.0f, sum1 = 0.0f, sumh = 0.0f;
    #pragma unroll
    for (int j = 0; j < 8; ++j) {
        float e0 = p[j].x - t[j].x, e1 = p[j].y - t[j].y;
        float e2 = p[j].z - t[j].z, e3 = p[j].w - t[j].w;
        float a0 = fabsf(e0), a1 = fabsf(e1), a2 = fabsf(e2), a3 = fabsf(e3);

        sum2 += e0*e0 + e1*e1 + e2*e2 + e3*e3;
        sum1 += a0 + a1 + a2 + a3;

        float h0 = (a0 <= DELTA) ? 0.5f*e0*e0 : DELTA*(a0 - 0.5f*DELTA);
        float h1 = (a1 <= DELTA) ? 0.5f*e1*e1 : DELTA*(a1 - 0.5f*DELTA);
        float h2 = (a2 <= DELTA) ? 0.5f*e2*e2 : DELTA*(a2 - 0.5f*DELTA);
        float h3 = (a3 <= DELTA) ? 0.5f*e3*e3 : DELTA*(a3 - 0.5f*DELTA);
        sumh += h0 + h1 + h2 + h3;
    }

    // wave-64 butterfly reduce
    #pragma unroll
    for (int off = 32; off > 0; off >>= 1) {
        sum2 += __shfl_down(sum2, off, 64);
        sum1 += __shfl_down(sum1, off, 64);
        sumh += __shfl_down(sumh, off, 64);
    }

    __shared__ float w2[4], w1[4], wh[4];
    __shared__ bool  last;
    const int wave = tid >> 6, lane = tid & 63;
    if (lane == 0) { w2[wave] = sum2; w1[wave] = sum1; wh[wave] = sumh; }
    __syncthreads();
    if (tid == 0) {
        float a = 0.f, c = 0.f, h = 0.f;
        #pragma unroll
        for (int w = 0; w < 4; ++w) { a += w2[w]; c += w1[w]; h += wh[w]; }
        const int o = (s * BPS + b) * 3;
        // agent-scope stores so the last block's reads can't hit stale cache
        __hip_atomic_store(&part[o + 0], a, __ATOMIC_RELAXED, __HIP_MEMORY_SCOPE_AGENT);
        __hip_atomic_store(&part[o + 1], c, __ATOMIC_RELAXED, __HIP_MEMORY_SCOPE_AGENT);
        __hip_atomic_store(&part[o + 2], h, __ATOMIC_RELAXED, __HIP_MEMORY_SCOPE_AGENT);
        __threadfence();   // release: partials visible before counter bump
        unsigned prev = __hip_atomic_fetch_add(counter, 1u, __ATOMIC_ACQ_REL,
                                               __HIP_MEMORY_SCOPE_AGENT);
        last = (prev == NBLOCKS - 1);
    }
    __syncthreads();
    if (!last) return;

    // ---- last block: final reduction (identical math to old stage2) ----
    __threadfence();   // acquire: invalidate caches before reading partials

    const int s2 = tid >> 5;          // 8 samples x 32 lanes
    const int ln = tid & 31;

    double A = 0.0, B = 0.0, H = 0.0;
    for (int k = ln; k < BPS; k += 32) {
        const int o = (s2 * BPS + k) * 3;
        A += (double)__hip_atomic_load(&part[o + 0], __ATOMIC_RELAXED, __HIP_MEMORY_SCOPE_AGENT);
        B += (double)__hip_atomic_load(&part[o + 1], __ATOMIC_RELAXED, __HIP_MEMORY_SCOPE_AGENT);
        H += (double)__hip_atomic_load(&part[o + 2], __ATOMIC_RELAXED, __HIP_MEMORY_SCOPE_AGENT);
    }
    #pragma unroll
    for (int off = 16; off > 0; off >>= 1) {
        A += __shfl_down(A, off, 32);
        B += __shfl_down(B, off, 32);
        H += __shfl_down(H, off, 32);
    }

    __shared__ double ps[8];
    if (ln == 0) {
        const double inv = 1.0 / PER_SAMPLE_D;
        double L2 = A * inv, L1 = B * inv, Hm = H * inv;
        bool use_l2 = (L2 <= 1.0) || (L2 < L1 * L1);
        ps[s2] = use_l2 ? L2 : Hm;
    }
    __syncthreads();
    if (tid == 0) {
        double acc = 0.0;
        #pragma unroll
        for (int i = 0; i < 8; ++i) acc += ps[i];
        out[0] = (float)(acc * 0.125);
    }
}

extern "C" void kernel_launch(void* const* d_in, const int* in_sizes, int n_in,
                              void* d_out, int out_size, void* d_ws, size_t ws_size,
                              hipStream_t stream) {
    const vf4* pred  = (const vf4*)d_in[0];   // y_pred_logits fp32
    const vf4* truth = (const vf4*)d_in[1];   // y_true fp32
    float*        part    = (float*)d_ws;                         // 48 KB
    unsigned int* counter = (unsigned int*)((char*)d_ws + 8 * BPS * 3 * sizeof(float));
    float*        out     = (float*)d_out;

    hipMemsetAsync(counter, 0, sizeof(unsigned int), stream);
    dim3 grid(BPS, 8);
    adap_fused<<<grid, TPB, 0, stream>>>(pred, truth, part, counter, out);
}

// Round 2
// 627.590 us; speedup vs baseline: 1.0302x; 1.0302x over previous
//
#include <hip/hip_runtime.h>

// AdapLoss — (8,1,160,160,160) fp32. Memory-bound reduction, 262 MB read.
// R6 = R5 with __builtin_nontemporal_load RESTORED. R5's plain loads made
// the compiler roll the 16-load batch (VGPR 128->32), collapsing MLP to
// ~2 loads/wave in flight -> 276 GB/s latency-bound (476 us). The nt
// builtin is what keeps all 16 loads issued back-to-back before the
// consume loop. Last-block fused reduction kept from R5 (saves the
// second launch + inter-node gap; math order identical to two-kernel
// version -> deterministic).

#define TPB 256
#define BPS 500                            // blocks per sample
constexpr int    F4_PER_SAMPLE = 1024000;  // 160^3 / 4
constexpr int    F4_PER_BLOCK  = 2048;     // 8 float4/thread * 256 threads
constexpr int    NBLOCKS       = 8 * BPS;  // 4000
constexpr double PER_SAMPLE_D  = 4096000.0;
constexpr float  DELTA = 5.0f;

typedef float vf4 __attribute__((ext_vector_type(4)));

__global__ __launch_bounds__(TPB, 4) void adap_fused(
    const vf4* __restrict__ pred,
    const vf4* __restrict__ truth,
    float* __restrict__ part,           // [8][BPS][3] in workspace
    unsigned int* __restrict__ counter, // 1 uint in workspace, memset to 0
    float* __restrict__ out)
{
    const int s   = blockIdx.y;
    const int b   = blockIdx.x;
    const int tid = threadIdx.x;
    const int base = s * F4_PER_SAMPLE + b * F4_PER_BLOCK + tid;

    // Issue all 16 loads back-to-back, interleaved (p0,t0,p1,t1,...) so the
    // j-th consume only needs vmcnt(14-2j) — queue stays deep while consuming.
    vf4 p[8], t[8];
    #pragma unroll
    for (int j = 0; j < 8; ++j) {
        p[j] = __builtin_nontemporal_load(&pred [base + j * TPB]);
        t[j] = __builtin_nontemporal_load(&truth[base + j * TPB]);
    }

    float sum2 = 0.0f, sum1 = 0.0f, sumh = 0.0f;
    #pragma unroll
    for (int j = 0; j < 8; ++j) {
        float e0 = p[j].x - t[j].x, e1 = p[j].y - t[j].y;
        float e2 = p[j].z - t[j].z, e3 = p[j].w - t[j].w;
        float a0 = fabsf(e0), a1 = fabsf(e1), a2 = fabsf(e2), a3 = fabsf(e3);

        sum2 += e0*e0 + e1*e1 + e2*e2 + e3*e3;
        sum1 += a0 + a1 + a2 + a3;

        float h0 = (a0 <= DELTA) ? 0.5f*e0*e0 : DELTA*(a0 - 0.5f*DELTA);
        float h1 = (a1 <= DELTA) ? 0.5f*e1*e1 : DELTA*(a1 - 0.5f*DELTA);
        float h2 = (a2 <= DELTA) ? 0.5f*e2*e2 : DELTA*(a2 - 0.5f*DELTA);
        float h3 = (a3 <= DELTA) ? 0.5f*e3*e3 : DELTA*(a3 - 0.5f*DELTA);
        sumh += h0 + h1 + h2 + h3;
    }

    // wave-64 butterfly reduce
    #pragma unroll
    for (int off = 32; off > 0; off >>= 1) {
        sum2 += __shfl_down(sum2, off, 64);
        sum1 += __shfl_down(sum1, off, 64);
        sumh += __shfl_down(sumh, off, 64);
    }

    __shared__ float w2[4], w1[4], wh[4];
    __shared__ bool  last;
    const int wave = tid >> 6, lane = tid & 63;
    if (lane == 0) { w2[wave] = sum2; w1[wave] = sum1; wh[wave] = sumh; }
    __syncthreads();
    if (tid == 0) {
        float a = 0.f, c = 0.f, h = 0.f;
        #pragma unroll
        for (int w = 0; w < 4; ++w) { a += w2[w]; c += w1[w]; h += wh[w]; }
        const int o = (s * BPS + b) * 3;
        // agent-scope stores so the last block's reads can't hit stale cache
        __hip_atomic_store(&part[o + 0], a, __ATOMIC_RELAXED, __HIP_MEMORY_SCOPE_AGENT);
        __hip_atomic_store(&part[o + 1], c, __ATOMIC_RELAXED, __HIP_MEMORY_SCOPE_AGENT);
        __hip_atomic_store(&part[o + 2], h, __ATOMIC_RELAXED, __HIP_MEMORY_SCOPE_AGENT);
        __threadfence();   // release: partials visible before counter bump
        unsigned prev = __hip_atomic_fetch_add(counter, 1u, __ATOMIC_ACQ_REL,
                                               __HIP_MEMORY_SCOPE_AGENT);
        last = (prev == NBLOCKS - 1);
    }
    __syncthreads();
    if (!last) return;

    // ---- last block: final reduction (identical math to old stage2) ----
    __threadfence();   // acquire: invalidate caches before reading partials

    const int s2 = tid >> 5;          // 8 samples x 32 lanes
    const int ln = tid & 31;

    double A = 0.0, B = 0.0, H = 0.0;
    for (int k = ln; k < BPS; k += 32) {
        const int o = (s2 * BPS + k) * 3;
        A += (double)__hip_atomic_load(&part[o + 0], __ATOMIC_RELAXED, __HIP_MEMORY_SCOPE_AGENT);
        B += (double)__hip_atomic_load(&part[o + 1], __ATOMIC_RELAXED, __HIP_MEMORY_SCOPE_AGENT);
        H += (double)__hip_atomic_load(&part[o + 2], __ATOMIC_RELAXED, __HIP_MEMORY_SCOPE_AGENT);
    }
    #pragma unroll
    for (int off = 16; off > 0; off >>= 1) {
        A += __shfl_down(A, off, 32);
        B += __shfl_down(B, off, 32);
        H += __shfl_down(H, off, 32);
    }

    __shared__ double ps[8];
    if (ln == 0) {
        const double inv = 1.0 / PER_SAMPLE_D;
        double L2 = A * inv, L1 = B * inv, Hm = H * inv;
        bool use_l2 = (L2 <= 1.0) || (L2 < L1 * L1);
        ps[s2] = use_l2 ? L2 : Hm;
    }
    __syncthreads();
    if (tid == 0) {
        double acc = 0.0;
        #pragma unroll
        for (int i = 0; i < 8; ++i) acc += ps[i];
        out[0] = (float)(acc * 0.125);
    }
}

extern "C" void kernel_launch(void* const* d_in, const int* in_sizes, int n_in,
                              void* d_out, int out_size, void* d_ws, size_t ws_size,
                              hipStream_t stream) {
    const vf4* pred  = (const vf4*)d_in[0];   // y_pred_logits fp32
    const vf4* truth = (const vf4*)d_in[1];   // y_true fp32
    float*        part    = (float*)d_ws;                         // 48 KB
    unsigned int* counter = (unsigned int*)((char*)d_ws + 8 * BPS * 3 * sizeof(float));
    float*        out     = (float*)d_out;

    hipMemsetAsync(counter, 0, sizeof(unsigned int), stream);
    dim3 grid(BPS, 8);
    adap_fused<<<grid, TPB, 0, stream>>>(pred, truth, part, counter, out);
}

// Round 3
// 621.745 us; speedup vs baseline: 1.0399x; 1.0094x over previous
//
#include <hip/hip_runtime.h>

// AdapLoss — (8,1,160,160,160) fp32. Memory-bound reduction, 262 MB read
// (~half served by Infinity Cache across iterations per FETCH_SIZE=128MB).
// R7 = R6 + explicit MLP pin: a single asm-volatile barrier consumes all
// 16 loaded float4 values, forcing 64 data VGPRs live at one point. R5/R6
// showed the fused tail flips the allocator to a 32-VGPR / rolled-load
// schedule (276-318 GB/s latency-bound) regardless of nt flags; the asm
// barrier makes the batch-issue pattern un-undoable: 16 back-to-back
// global_load_dwordx4, one vmcnt(0), waitless consume.

#define TPB 256
#define BPS 500                            // blocks per sample
constexpr int    F4_PER_SAMPLE = 1024000;  // 160^3 / 4
constexpr int    F4_PER_BLOCK  = 2048;     // 8 float4/thread * 256 threads
constexpr int    NBLOCKS       = 8 * BPS;  // 4000
constexpr double PER_SAMPLE_D  = 4096000.0;
constexpr float  DELTA = 5.0f;

typedef float vf4 __attribute__((ext_vector_type(4)));

__global__ __launch_bounds__(TPB, 4) void adap_fused(
    const vf4* __restrict__ pred,
    const vf4* __restrict__ truth,
    float* __restrict__ part,           // [8][BPS][3] in workspace
    unsigned int* __restrict__ counter, // 1 uint in workspace, memset to 0
    float* __restrict__ out)
{
    const int s   = blockIdx.y;
    const int b   = blockIdx.x;
    const int tid = threadIdx.x;
    const int base = s * F4_PER_SAMPLE + b * F4_PER_BLOCK + tid;

    // Issue all 16 loads; the asm barrier below forces every value live
    // simultaneously -> compiler must emit 16 back-to-back loads.
    vf4 p[8], t[8];
    #pragma unroll
    for (int j = 0; j < 8; ++j) {
        p[j] = __builtin_nontemporal_load(&pred [base + j * TPB]);
        t[j] = __builtin_nontemporal_load(&truth[base + j * TPB]);
    }
    asm volatile("" ::
        "v"(p[0]), "v"(p[1]), "v"(p[2]), "v"(p[3]),
        "v"(p[4]), "v"(p[5]), "v"(p[6]), "v"(p[7]),
        "v"(t[0]), "v"(t[1]), "v"(t[2]), "v"(t[3]),
        "v"(t[4]), "v"(t[5]), "v"(t[6]), "v"(t[7]));

    float sum2 = 0.0f, sum1 = 0.0f, sumh = 0.0f;
    #pragma unroll
    for (int j = 0; j < 8; ++j) {
        float e0 = p[j].x - t[j].x, e1 = p[j].y - t[j].y;
        float e2 = p[j].z - t[j].z, e3 = p[j].w - t[j].w;
        float a0 = fabsf(e0), a1 = fabsf(e1), a2 = fabsf(e2), a3 = fabsf(e3);

        sum2 += e0*e0 + e1*e1 + e2*e2 + e3*e3;
        sum1 += a0 + a1 + a2 + a3;

        float h0 = (a0 <= DELTA) ? 0.5f*e0*e0 : DELTA*(a0 - 0.5f*DELTA);
        float h1 = (a1 <= DELTA) ? 0.5f*e1*e1 : DELTA*(a1 - 0.5f*DELTA);
        float h2 = (a2 <= DELTA) ? 0.5f*e2*e2 : DELTA*(a2 - 0.5f*DELTA);
        float h3 = (a3 <= DELTA) ? 0.5f*e3*e3 : DELTA*(a3 - 0.5f*DELTA);
        sumh += h0 + h1 + h2 + h3;
    }

    // wave-64 butterfly reduce
    #pragma unroll
    for (int off = 32; off > 0; off >>= 1) {
        sum2 += __shfl_down(sum2, off, 64);
        sum1 += __shfl_down(sum1, off, 64);
        sumh += __shfl_down(sumh, off, 64);
    }

    __shared__ float w2[4], w1[4], wh[4];
    __shared__ bool  last;
    const int wave = tid >> 6, lane = tid & 63;
    if (lane == 0) { w2[wave] = sum2; w1[wave] = sum1; wh[wave] = sumh; }
    __syncthreads();
    if (tid == 0) {
        float a = 0.f, c = 0.f, h = 0.f;
        #pragma unroll
        for (int w = 0; w < 4; ++w) { a += w2[w]; c += w1[w]; h += wh[w]; }
        const int o = (s * BPS + b) * 3;
        // agent-scope stores so the last block's reads can't hit stale cache
        __hip_atomic_store(&part[o + 0], a, __ATOMIC_RELAXED, __HIP_MEMORY_SCOPE_AGENT);
        __hip_atomic_store(&part[o + 1], c, __ATOMIC_RELAXED, __HIP_MEMORY_SCOPE_AGENT);
        __hip_atomic_store(&part[o + 2], h, __ATOMIC_RELAXED, __HIP_MEMORY_SCOPE_AGENT);
        __threadfence();   // release: partials visible before counter bump
        unsigned prev = __hip_atomic_fetch_add(counter, 1u, __ATOMIC_ACQ_REL,
                                               __HIP_MEMORY_SCOPE_AGENT);
        last = (prev == NBLOCKS - 1);
    }
    __syncthreads();
    if (!last) return;

    // ---- last block: final reduction (identical math to old stage2) ----
    __threadfence();   // acquire: invalidate caches before reading partials

    const int s2 = tid >> 5;          // 8 samples x 32 lanes
    const int ln = tid & 31;

    double A = 0.0, B = 0.0, H = 0.0;
    for (int k = ln; k < BPS; k += 32) {
        const int o = (s2 * BPS + k) * 3;
        A += (double)__hip_atomic_load(&part[o + 0], __ATOMIC_RELAXED, __HIP_MEMORY_SCOPE_AGENT);
        B += (double)__hip_atomic_load(&part[o + 1], __ATOMIC_RELAXED, __HIP_MEMORY_SCOPE_AGENT);
        H += (double)__hip_atomic_load(&part[o + 2], __ATOMIC_RELAXED, __HIP_MEMORY_SCOPE_AGENT);
    }
    #pragma unroll
    for (int off = 16; off > 0; off >>= 1) {
        A += __shfl_down(A, off, 32);
        B += __shfl_down(B, off, 32);
        H += __shfl_down(H, off, 32);
    }

    __shared__ double ps[8];
    if (ln == 0) {
        const double inv = 1.0 / PER_SAMPLE_D;
        double L2 = A * inv, L1 = B * inv, Hm = H * inv;
        bool use_l2 = (L2 <= 1.0) || (L2 < L1 * L1);
        ps[s2] = use_l2 ? L2 : Hm;
    }
    __syncthreads();
    if (tid == 0) {
        double acc = 0.0;
        #pragma unroll
        for (int i = 0; i < 8; ++i) acc += ps[i];
        out[0] = (float)(acc * 0.125);
    }
}

extern "C" void kernel_launch(void* const* d_in, const int* in_sizes, int n_in,
                              void* d_out, int out_size, void* d_ws, size_t ws_size,
                              hipStream_t stream) {
    const vf4* pred  = (const vf4*)d_in[0];   // y_pred_logits fp32
    const vf4* truth = (const vf4*)d_in[1];   // y_true fp32
    float*        part    = (float*)d_ws;                         // 48 KB
    unsigned int* counter = (unsigned int*)((char*)d_ws + 8 * BPS * 3 * sizeof(float));
    float*        out     = (float*)d_out;

    hipMemsetAsync(counter, 0, sizeof(unsigned int), stream);
    dim3 grid(BPS, 8);
    adap_fused<<<grid, TPB, 0, stream>>>(pred, truth, part, counter, out);
}

// Round 4
// 247.249 us; speedup vs baseline: 2.6150x; 2.5146x over previous
//
#include <hip/hip_runtime.h>

// AdapLoss — (8,1,160,160,160) fp32. Memory-bound reduction, 262 MB read
// (~128 MB served by Infinity Cache across iterations per R5-R7 FETCH_SIZE).
// R8 = revert to the PROVEN two-kernel R4 structure (every fused variant
// R5-R7 made the allocator roll the load batch: VGPR 32-36, ~310 GB/s,
// 413-476 us; two-kernel R4 batched at 128 VGPR and ran 247.5 us total),
// with one upgrade: per-thread batch doubled 16->32 float4 (p[16],t[16],
// 512 B/thread) under __launch_bounds__(256,3) (~170 VGPR budget, need
// ~145). Little's law: 3 waves/EU x 32 loads x 16B = 6 KB/CU in flight
// -> ~4.1+ TB/s vs R4's ~2.7-3.7. Blocks halve to 2000 -> half the
// reduce-tail overhead.

#define TPB 256
#define BPS 250                            // blocks per sample
constexpr int    F4_PER_SAMPLE = 1024000;  // 160^3 / 4
constexpr int    F4_PER_BLOCK  = 4096;     // 16 float4/thread * 256 threads (per array)
constexpr double PER_SAMPLE_D  = 4096000.0;
constexpr float  DELTA = 5.0f;

typedef float vf4 __attribute__((ext_vector_type(4)));

__global__ __launch_bounds__(TPB, 3) void adap_stage1(
    const vf4* __restrict__ pred,
    const vf4* __restrict__ truth,
    float* __restrict__ part)   // [8][BPS][3]
{
    const int s   = blockIdx.y;
    const int b   = blockIdx.x;
    const int tid = threadIdx.x;
    const int base = s * F4_PER_SAMPLE + b * F4_PER_BLOCK + tid;

    // Issue all 32 loads back-to-back, interleaved (p0,t0,p1,t1,...) so the
    // j-th consume only needs vmcnt(30-2j) — queue stays deep while consuming.
    vf4 p[16], t[16];
    #pragma unroll
    for (int j = 0; j < 16; ++j) {
        p[j] = __builtin_nontemporal_load(&pred [base + j * TPB]);
        t[j] = __builtin_nontemporal_load(&truth[base + j * TPB]);
    }
    asm volatile("" ::
        "v"(p[0]), "v"(p[1]), "v"(p[2]),  "v"(p[3]),
        "v"(p[4]), "v"(p[5]), "v"(p[6]),  "v"(p[7]),
        "v"(p[8]), "v"(p[9]), "v"(p[10]), "v"(p[11]),
        "v"(p[12]),"v"(p[13]),"v"(p[14]), "v"(p[15]),
        "v"(t[0]), "v"(t[1]), "v"(t[2]),  "v"(t[3]),
        "v"(t[4]), "v"(t[5]), "v"(t[6]),  "v"(t[7]),
        "v"(t[8]), "v"(t[9]), "v"(t[10]), "v"(t[11]),
        "v"(t[12]),"v"(t[13]),"v"(t[14]), "v"(t[15]));

    float sum2 = 0.0f, sum1 = 0.0f, sumh = 0.0f;
    #pragma unroll
    for (int j = 0; j < 16; ++j) {
        float e0 = p[j].x - t[j].x, e1 = p[j].y - t[j].y;
        float e2 = p[j].z - t[j].z, e3 = p[j].w - t[j].w;
        float a0 = fabsf(e0), a1 = fabsf(e1), a2 = fabsf(e2), a3 = fabsf(e3);

        sum2 += e0*e0 + e1*e1 + e2*e2 + e3*e3;
        sum1 += a0 + a1 + a2 + a3;

        float h0 = (a0 <= DELTA) ? 0.5f*e0*e0 : DELTA*(a0 - 0.5f*DELTA);
        float h1 = (a1 <= DELTA) ? 0.5f*e1*e1 : DELTA*(a1 - 0.5f*DELTA);
        float h2 = (a2 <= DELTA) ? 0.5f*e2*e2 : DELTA*(a2 - 0.5f*DELTA);
        float h3 = (a3 <= DELTA) ? 0.5f*e3*e3 : DELTA*(a3 - 0.5f*DELTA);
        sumh += h0 + h1 + h2 + h3;
    }

    // wave-64 butterfly reduce
    #pragma unroll
    for (int off = 32; off > 0; off >>= 1) {
        sum2 += __shfl_down(sum2, off, 64);
        sum1 += __shfl_down(sum1, off, 64);
        sumh += __shfl_down(sumh, off, 64);
    }

    __shared__ float w2[4], w1[4], wh[4];
    const int wave = tid >> 6, lane = tid & 63;
    if (lane == 0) { w2[wave] = sum2; w1[wave] = sum1; wh[wave] = sumh; }
    __syncthreads();
    if (tid == 0) {
        float a = 0.f, c = 0.f, h = 0.f;
        #pragma unroll
        for (int w = 0; w < 4; ++w) { a += w2[w]; c += w1[w]; h += wh[w]; }
        const int o = (s * BPS + b) * 3;
        part[o + 0] = a;
        part[o + 1] = c;
        part[o + 2] = h;
    }
}

__global__ __launch_bounds__(TPB) void adap_stage2(
    const float* __restrict__ part,   // [8][BPS][3]
    float* __restrict__ out)
{
    const int tid  = threadIdx.x;
    const int s    = tid >> 5;        // 8 samples x 32 lanes
    const int lane = tid & 31;

    double a = 0.0, b = 0.0, h = 0.0;
    for (int k = lane; k < BPS; k += 32) {
        const float* p = part + (s * BPS + k) * 3;
        a += (double)p[0];
        b += (double)p[1];
        h += (double)p[2];
    }
    #pragma unroll
    for (int off = 16; off > 0; off >>= 1) {
        a += __shfl_down(a, off, 32);
        b += __shfl_down(b, off, 32);
        h += __shfl_down(h, off, 32);
    }

    __shared__ double ps[8];
    if (lane == 0) {
        const double inv = 1.0 / PER_SAMPLE_D;
        double L2 = a * inv, L1 = b * inv, H = h * inv;
        bool use_l2 = (L2 <= 1.0) || (L2 < L1 * L1);
        ps[s] = use_l2 ? L2 : H;
    }
    __syncthreads();
    if (tid == 0) {
        double acc = 0.0;
        #pragma unroll
        for (int i = 0; i < 8; ++i) acc += ps[i];
        out[0] = (float)(acc * 0.125);
    }
}

extern "C" void kernel_launch(void* const* d_in, const int* in_sizes, int n_in,
                              void* d_out, int out_size, void* d_ws, size_t ws_size,
                              hipStream_t stream) {
    const vf4* pred  = (const vf4*)d_in[0];   // y_pred_logits fp32
    const vf4* truth = (const vf4*)d_in[1];   // y_true fp32
    float* part = (float*)d_ws;               // 8*250*3 floats = 24 KB
    float* out  = (float*)d_out;

    dim3 grid1(BPS, 8);
    adap_stage1<<<grid1, TPB, 0, stream>>>(pred, truth, part);
    adap_stage2<<<1, TPB, 0, stream>>>(part, out);
}